// Round 13
// baseline (130.694 us; speedup 1.0000x reference)
//
#include <hip/hip_runtime.h>
#include <cstdint>

#define BB 2
#define NN 16384
#define MM 2048
#define CC 64
#define SS 32
#define NWAVE 8
#define NCH 64    // 64 chunks of 256 points
#define NSTEP 8   // NCH / NWAVE

__device__ __forceinline__ float dist2(float qx, float qy, float qz,
                                       float px, float py, float pz) {
    // Match reference rounding: explicit mul/add, no FMA contraction.
    // Verified exact (absmax=0.0) in Rounds 4/8/9/10/11 — do not change.
    float dx = __fsub_rn(qx, px), dy = __fsub_rn(qy, py), dz = __fsub_rn(qz, pz);
    return __fadd_rn(__fadd_rn(__fmul_rn(dx, dx), __fmul_rn(dy, dy)), __fmul_rn(dz, dz));
}

// features (B,C,N) -> feat_t (B,N,C), tiled 32x32 through LDS.
__global__ __launch_bounds__(256) void transpose_feat(
    const float* __restrict__ f, float* __restrict__ ft) {
    __shared__ float tile[32][33];
    int bid = blockIdx.x;
    int n0 = (bid & 511) * 32;          // N/32 = 512 tiles
    int c0 = ((bid >> 9) & 1) * 32;     // C/32 = 2 tiles
    int b = bid >> 10;                  // B = 2
    int tx = threadIdx.x & 31, ty = threadIdx.x >> 5;  // (32,8)
#pragma unroll
    for (int k = 0; k < 32; k += 8)
        tile[ty + k][tx] = f[((size_t)(b * CC + c0 + ty + k)) * NN + n0 + tx];
    __syncthreads();
#pragma unroll
    for (int k = 0; k < 32; k += 8)
        ft[((size_t)(b * NN + n0 + ty + k)) * CC + c0 + tx] = tile[tx][ty + k];
}

// One block (8 waves, 512 thr) per query.
// Step-interleaved scan: at step t, wave w scans chunk t*8+w (256 points);
// after each step the block checks whether the scanned prefix already holds
// >=32 matches (capped counts: cap at 32/chunk is lossless for the top-32;
// capped-sum >= 32 iff true-sum >= 32). Typical stop: 1 step; worst 8.
// Merge + gather + stores are the Round-11-verified phases.
__global__ __launch_bounds__(512) void qg_kernel(
    const float* __restrict__ xyz, const float* __restrict__ new_xyz,
    const float* __restrict__ feat_t, float* __restrict__ out) {
    constexpr float R_IN2 = 0.05f * 0.05f;
    constexpr float R_OUT2 = 0.2f * 0.2f;
    __shared__ int idxC[NCH][SS];   // per-chunk kept matches (rank < 32)
    __shared__ int cC[NCH];         // per-chunk capped counts
    __shared__ int sTotal;
    __shared__ int sStop;
    __shared__ int idxS[SS];
    __shared__ float fbuf[SS][CC + 4];  // 16B-aligned rows (stride 68)

    int tid = threadIdx.x;
    int lane = tid & 63;
    int w = tid >> 6;  // wave id
    int bm = blockIdx.x;
    int b = bm >> 11;
    int m = bm & 2047;

    float qx = new_xyz[(size_t)bm * 3 + 0];
    float qy = new_xyz[(size_t)bm * 3 + 1];
    float qz = new_xyz[(size_t)bm * 3 + 2];

    if (tid < NCH) cC[tid] = 0;
    if (tid == 0) { sTotal = 0; sStop = 0; }
    __syncthreads();

    // Phase 1: step-interleaved scan.
    unsigned long long below = (1ull << lane) - 1ull;
    for (int t = 0; t < NSTEP; ++t) {
        int ch = t * NWAVE + w;
        int j0 = ch * 256;
        float px[4], py[4], pz[4];
        const float* pp = xyz + ((size_t)(b * NN + j0 + lane)) * 3;
#pragma unroll
        for (int u = 0; u < 4; ++u) {
            px[u] = pp[u * 192 + 0];
            py[u] = pp[u * 192 + 1];
            pz[u] = pp[u * 192 + 2];
        }
        int c = 0;
#pragma unroll
        for (int u = 0; u < 4; ++u) {
            float d2 = dist2(qx, qy, qz, px[u], py[u], pz[u]);
            bool inshell = (d2 >= R_IN2) && (d2 < R_OUT2);
            unsigned long long mk = __ballot(inshell);
            if (inshell) {
                int r = c + __popcll(mk & below);
                if (r < SS) idxC[ch][r] = j0 + u * 64 + lane;
            }
            c += __popcll(mk);
        }
        if (lane == 0) cC[ch] = c < SS ? c : SS;
        __syncthreads();
        if (tid == 0) {
            int tot = sTotal;
#pragma unroll
            for (int k = 0; k < NWAVE; ++k) tot += cC[t * NWAVE + k];
            sTotal = tot;
            if (tot >= SS) sStop = 1;
        }
        __syncthreads();
        if (sStop) break;
    }

    // Merge: threads 0..31 resolve final slot indices (prefix over chunks).
    if (tid < SS) {
        int r = tid;
        int acc = 0, pick = -1, off = 0, s0 = -1;
        for (int ch = 0; ch < NCH; ++ch) {
            int cs = cC[ch];
            if (pick < 0 && r < acc + cs) { pick = ch; off = r - acc; }
            if (s0 < 0 && cs > 0) s0 = ch;
            acc += cs;
        }
        int cnt = acc < SS ? acc : SS;
        int j;
        if (r < cnt) j = idxC[pick][off];
        else j = (s0 >= 0) ? idxC[s0][0] : 0;  // first match, or 0 if none
        idxS[r] = j;
        if (r == 0) out[bm] = (float)cnt;  // idx_cnt as float
    }
    __syncthreads();

    float* gout = out + BB * MM;

    // Phase 2: gather 32 slots x 64 ch — one float4 load per thread.
    {
        int sl = tid >> 4, c4 = tid & 15;
        float4 v = ((const float4*)(feat_t + ((size_t)b * NN + idxS[sl]) * CC))[c4];
        *((float4*)&fbuf[sl][c4 * 4]) = v;
    }

    // xyz channels 0..2: grouped_xyz = xyz[j] - new_xyz[m] (threads 0..95).
    if (tid < 96) {
        int ch = tid >> 5, s = tid & 31;
        int j = idxS[s];
        float pv = xyz[((size_t)(b * NN) + j) * 3 + ch];
        float qv = new_xyz[(size_t)bm * 3 + ch];
        gout[((size_t)(b * 67 + ch) * MM + m) * SS + s] = __fsub_rn(pv, qv);
    }
    __syncthreads();

    // Phase 3: feature channels — one float4 store per thread.
    {
        int ch = tid >> 3, sg = tid & 7;
        float4 v = make_float4(fbuf[sg * 4 + 0][ch], fbuf[sg * 4 + 1][ch],
                               fbuf[sg * 4 + 2][ch], fbuf[sg * 4 + 3][ch]);
        *((float4*)&gout[((size_t)(b * 67 + 3 + ch) * MM + m) * SS + sg * 4]) = v;
    }
}

// Fallback (ws too small): monolithic verified-semantics kernel, native layouts.
__global__ __launch_bounds__(256) void query_group_fallback(
    const float* __restrict__ xyz, const float* __restrict__ new_xyz,
    const float* __restrict__ features, float* __restrict__ out) {
    constexpr float R_IN2 = 0.05f * 0.05f;
    constexpr float R_OUT2 = 0.2f * 0.2f;
    __shared__ int idxS[4][SS];

    int lane = threadIdx.x & 63;
    int w = threadIdx.x >> 6;
    int bm = blockIdx.x * 4 + w;
    int b = bm >> 11;
    int m = bm & 2047;

    float qx = new_xyz[(size_t)bm * 3 + 0];
    float qy = new_xyz[(size_t)bm * 3 + 1];
    float qz = new_xyz[(size_t)bm * 3 + 2];

    if (lane == 0) idxS[w][0] = 0;

    unsigned long long below = (1ull << lane) - 1ull;
    int cnt = 0;
    for (int j0 = 0; j0 < NN; j0 += 256) {
        float px[4], py[4], pz[4];
        const float* pp = xyz + ((size_t)(b * NN + j0 + lane)) * 3;
#pragma unroll
        for (int u = 0; u < 4; ++u) {
            px[u] = pp[u * 192 + 0];
            py[u] = pp[u * 192 + 1];
            pz[u] = pp[u * 192 + 2];
        }
#pragma unroll
        for (int u = 0; u < 4; ++u) {
            float d2 = dist2(qx, qy, qz, px[u], py[u], pz[u]);
            bool inshell = (d2 >= R_IN2) && (d2 < R_OUT2);
            unsigned long long mk = __ballot(inshell);
            if (inshell) {
                int r = cnt + __popcll(mk & below);
                if (r < SS) idxS[w][r] = j0 + u * 64 + lane;
            }
            cnt += __popcll(mk);
        }
        if (cnt >= SS) break;
    }
    if (cnt > SS) cnt = SS;
    if (lane == 0) out[bm] = (float)cnt;

    float* gout = out + BB * MM;
    int s = lane & 31, half = lane >> 5;
    int j = (s < cnt) ? idxS[w][s] : idxS[w][0];
    const float* pp = xyz + ((size_t)(b * NN) + j) * 3;
    float px = pp[0], py = pp[1], pz = pp[2];
    float v01 = half ? __fsub_rn(py, qy) : __fsub_rn(px, qx);
    gout[((size_t)(b * 67 + half) * MM + m) * SS + s] = v01;
    if (half == 0) gout[((size_t)(b * 67 + 2) * MM + m) * SS + s] = __fsub_rn(pz, qz);
#pragma unroll
    for (int k = 0; k < 32; ++k) {
        int ch = 2 * k + half;
        float v = features[((size_t)(b * CC + ch)) * NN + j];
        gout[((size_t)(b * 67 + 3 + ch) * MM + m) * SS + s] = v;
    }
}

extern "C" void kernel_launch(void* const* d_in, const int* in_sizes, int n_in,
                              void* d_out, int out_size, void* d_ws, size_t ws_size,
                              hipStream_t stream) {
    const float* xyz = (const float*)d_in[0];
    const float* new_xyz = (const float*)d_in[1];
    const float* features = (const float*)d_in[2];
    float* out = (float*)d_out;

    const size_t featT_bytes = (size_t)BB * NN * CC * 4;  // 8,388,608
    bool fast = ws_size >= featT_bytes;

    if (fast) {
        float* feat_t = (float*)d_ws;
        transpose_feat<<<2048, 256, 0, stream>>>(features, feat_t);
        qg_kernel<<<BB * MM, 512, 0, stream>>>(xyz, new_xyz, feat_t, out);
    } else {
        query_group_fallback<<<BB * MM / 4, 256, 0, stream>>>(xyz, new_xyz, features, out);
    }
}

// Round 14
// 94.893 us; speedup vs baseline: 1.3773x; 1.3773x over previous
//
#include <hip/hip_runtime.h>
#include <cstdint>

#define BB 2
#define NN 16384
#define MM 2048
#define CC 64
#define SS 32
#define PRE 2048           // K1 prefix length
#define SEG2 1792          // (NN - PRE) / 8 per K2 wave
#define WPB 4

// ws: feat_t [0, 8 MB) | pidx [8MB, +524288) | pcnt [+524288, +16384)

__device__ __forceinline__ float dist2(float qx, float qy, float qz,
                                       float px, float py, float pz) {
    // Match reference rounding: explicit mul/add, no FMA contraction.
    // Verified exact (absmax=0.0) in Rounds 4/8/9/10/11/13 — do not change.
    float dx = __fsub_rn(qx, px), dy = __fsub_rn(qy, py), dz = __fsub_rn(qz, pz);
    return __fadd_rn(__fadd_rn(__fmul_rn(dx, dx), __fmul_rn(dy, dy)), __fmul_rn(dz, dz));
}

// features (B,C,N) -> feat_t (B,N,C), tiled 32x32 through LDS.
__global__ __launch_bounds__(256) void transpose_feat(
    const float* __restrict__ f, float* __restrict__ ft) {
    __shared__ float tile[32][33];
    int bid = blockIdx.x;
    int n0 = (bid & 511) * 32;
    int c0 = ((bid >> 9) & 1) * 32;
    int b = bid >> 10;
    int tx = threadIdx.x & 31, ty = threadIdx.x >> 5;
#pragma unroll
    for (int k = 0; k < 32; k += 8)
        tile[ty + k][tx] = f[((size_t)(b * CC + c0 + ty + k)) * NN + n0 + tx];
    __syncthreads();
#pragma unroll
    for (int k = 0; k < 32; k += 8)
        ft[((size_t)(b * NN + n0 + ty + k)) * CC + c0 + tx] = tile[tx][ty + k];
}

// K1: one wave per query scans prefix [0, PRE) only (max 8 iters — bounded,
// no tail). Complete queries (cnt>=32 in prefix: ranks are global since the
// prefix starts at 0) do the verified gather+store inline. Pending queries
// store partial count+indices for K2.
__global__ __launch_bounds__(256) void k1_scan_group(
    const float* __restrict__ xyz, const float* __restrict__ new_xyz,
    const float* __restrict__ feat_t, int* __restrict__ pcnt,
    int* __restrict__ pidx, float* __restrict__ out) {
    constexpr float R_IN2 = 0.05f * 0.05f;
    constexpr float R_OUT2 = 0.2f * 0.2f;
    __shared__ int idxS[WPB][SS];
    __shared__ float fbuf[WPB][SS][CC + 4];

    int lane = threadIdx.x & 63;
    int w = threadIdx.x >> 6;
    int bm = blockIdx.x * WPB + w;
    int b = bm >> 11;
    int m = bm & 2047;

    float qx = new_xyz[(size_t)bm * 3 + 0];
    float qy = new_xyz[(size_t)bm * 3 + 1];
    float qz = new_xyz[(size_t)bm * 3 + 2];

    unsigned long long below = (1ull << lane) - 1ull;
    int cnt = 0;
    for (int j0 = 0; j0 < PRE; j0 += 256) {
        float px[4], py[4], pz[4];
        const float* pp = xyz + ((size_t)(b * NN + j0 + lane)) * 3;
#pragma unroll
        for (int u = 0; u < 4; ++u) {
            px[u] = pp[u * 192 + 0];
            py[u] = pp[u * 192 + 1];
            pz[u] = pp[u * 192 + 2];
        }
#pragma unroll
        for (int u = 0; u < 4; ++u) {
            float d2 = dist2(qx, qy, qz, px[u], py[u], pz[u]);
            bool inshell = (d2 >= R_IN2) && (d2 < R_OUT2);
            unsigned long long mk = __ballot(inshell);
            if (inshell) {
                int r = cnt + __popcll(mk & below);
                if (r < SS) idxS[w][r] = j0 + u * 64 + lane;
            }
            cnt += __popcll(mk);
        }
        if (cnt >= SS) break;  // wave-uniform
    }
    bool complete = cnt >= SS;
    if (cnt > SS) cnt = SS;

    if (!complete) {
        if (lane == 0) pcnt[bm] = cnt;
        if (lane < cnt) pidx[bm * SS + lane] = idxS[w][lane];
        return;  // wave-uniform exit; K2 finishes this query
    }

    if (lane == 0) { pcnt[bm] = SS; out[bm] = 32.0f; }

    float* gout = out + BB * MM;

    // Phase 2 (verified): 8 float4 loads in flight -> fbuf.
    {
        int s4 = lane >> 4, c4 = lane & 15;
        int jj[8];
#pragma unroll
        for (int it = 0; it < 8; ++it) jj[it] = idxS[w][it * 4 + s4];
        float4 vv[8];
#pragma unroll
        for (int it = 0; it < 8; ++it)
            vv[it] = ((const float4*)(feat_t + ((size_t)b * NN + jj[it]) * CC))[c4];
#pragma unroll
        for (int it = 0; it < 8; ++it)
            *((float4*)&fbuf[w][it * 4 + s4][c4 * 4]) = vv[it];
    }

    // xyz channels (verified): grouped_xyz = xyz[j] - new_xyz[m].
    {
        int s = lane & 31, half = lane >> 5;
        int j = idxS[w][s];
        const float* pp = xyz + ((size_t)(b * NN) + j) * 3;
        float px = pp[0], py = pp[1], pz = pp[2];
        float v01 = half ? __fsub_rn(py, qy) : __fsub_rn(px, qx);
        gout[((size_t)(b * 67 + half) * MM + m) * SS + s] = v01;
        if (half == 0)
            gout[((size_t)(b * 67 + 2) * MM + m) * SS + s] = __fsub_rn(pz, qz);
    }

    // Phase 3 (verified): float4 channel-major stores.
    {
        int ch8 = lane >> 3, sg = lane & 7;
#pragma unroll
        for (int it = 0; it < 8; ++it) {
            int ch = it * 8 + ch8;
            float4 v = make_float4(fbuf[w][sg * 4 + 0][ch], fbuf[w][sg * 4 + 1][ch],
                                   fbuf[w][sg * 4 + 2][ch], fbuf[w][sg * 4 + 3][ch]);
            *((float4*)&gout[((size_t)(b * 67 + 3 + ch) * MM + m) * SS + sg * 4]) = v;
        }
    }
}

// K2: one block per query; ~85% exit on the flag. Pending: 8-wave segmented
// scan of [PRE, NN) (verified R11 pattern; local cap lossless), 9-list merge
// (K1 partial = list 0), verified 512-thread gather + stores.
__global__ __launch_bounds__(512) void k2_finish(
    const float* __restrict__ xyz, const float* __restrict__ new_xyz,
    const float* __restrict__ feat_t, const int* __restrict__ pcnt,
    const int* __restrict__ pidx, float* __restrict__ out) {
    constexpr float R_IN2 = 0.05f * 0.05f;
    constexpr float R_OUT2 = 0.2f * 0.2f;
    int bm = blockIdx.x;
    int c0 = pcnt[bm];          // block-uniform
    if (c0 >= SS) return;       // K1 completed this query

    __shared__ int idxC[9][SS];
    __shared__ int cC[9];
    __shared__ int idxS[SS];
    __shared__ float fbuf[SS][CC + 4];

    int tid = threadIdx.x;
    int lane = tid & 63;
    int w = tid >> 6;
    int b = bm >> 11;
    int m = bm & 2047;

    float qx = new_xyz[(size_t)bm * 3 + 0];
    float qy = new_xyz[(size_t)bm * 3 + 1];
    float qz = new_xyz[(size_t)bm * 3 + 2];

    if (tid < c0) idxC[0][tid] = pidx[bm * SS + tid];
    if (tid == 0) cC[0] = c0;

    unsigned long long below = (1ull << lane) - 1ull;
    int c = 0;
    int base = PRE + w * SEG2;
    for (int j0 = base; j0 < base + SEG2; j0 += 256) {
        float px[4], py[4], pz[4];
        const float* pp = xyz + ((size_t)(b * NN + j0 + lane)) * 3;
#pragma unroll
        for (int u = 0; u < 4; ++u) {
            px[u] = pp[u * 192 + 0];
            py[u] = pp[u * 192 + 1];
            pz[u] = pp[u * 192 + 2];
        }
#pragma unroll
        for (int u = 0; u < 4; ++u) {
            float d2 = dist2(qx, qy, qz, px[u], py[u], pz[u]);
            bool inshell = (d2 >= R_IN2) && (d2 < R_OUT2);
            unsigned long long mk = __ballot(inshell);
            if (inshell) {
                int r = c + __popcll(mk & below);
                if (r < SS) idxC[1 + w][r] = j0 + u * 64 + lane;
            }
            c += __popcll(mk);
        }
        if (c >= SS) break;  // wave-uniform local exit (rank>=32 never needed)
    }
    if (lane == 0) cC[1 + w] = c < SS ? c : SS;
    __syncthreads();

    // Merge (verified pattern, 9 lists).
    if (tid < SS) {
        int r = tid, acc = 0, pick = -1, off = 0, s0 = -1;
#pragma unroll
        for (int l = 0; l < 9; ++l) {
            int cs = cC[l];
            if (pick < 0 && r < acc + cs) { pick = l; off = r - acc; }
            if (s0 < 0 && cs > 0) s0 = l;
            acc += cs;
        }
        int cnt = acc < SS ? acc : SS;
        int j;
        if (r < cnt) j = idxC[pick][off];
        else j = (s0 >= 0) ? idxC[s0][0] : 0;
        idxS[r] = j;
        if (r == 0) out[bm] = (float)cnt;
    }
    __syncthreads();

    float* gout = out + BB * MM;

    // Gather (verified): one float4 load per thread.
    {
        int sl = tid >> 4, c4 = tid & 15;
        float4 v = ((const float4*)(feat_t + ((size_t)b * NN + idxS[sl]) * CC))[c4];
        *((float4*)&fbuf[sl][c4 * 4]) = v;
    }

    if (tid < 96) {
        int ch = tid >> 5, s = tid & 31;
        int j = idxS[s];
        float pv = xyz[((size_t)(b * NN) + j) * 3 + ch];
        float qv = new_xyz[(size_t)bm * 3 + ch];
        gout[((size_t)(b * 67 + ch) * MM + m) * SS + s] = __fsub_rn(pv, qv);
    }
    __syncthreads();

    // Stores (verified): one float4 per thread.
    {
        int ch = tid >> 3, sg = tid & 7;
        float4 v = make_float4(fbuf[sg * 4 + 0][ch], fbuf[sg * 4 + 1][ch],
                               fbuf[sg * 4 + 2][ch], fbuf[sg * 4 + 3][ch]);
        *((float4*)&gout[((size_t)(b * 67 + 3 + ch) * MM + m) * SS + sg * 4]) = v;
    }
}

// Fallback (ws too small): verified monolith, native layouts.
__global__ __launch_bounds__(256) void query_group_fallback(
    const float* __restrict__ xyz, const float* __restrict__ new_xyz,
    const float* __restrict__ features, float* __restrict__ out) {
    constexpr float R_IN2 = 0.05f * 0.05f;
    constexpr float R_OUT2 = 0.2f * 0.2f;
    __shared__ int idxS[4][SS];

    int lane = threadIdx.x & 63;
    int w = threadIdx.x >> 6;
    int bm = blockIdx.x * 4 + w;
    int b = bm >> 11;
    int m = bm & 2047;

    float qx = new_xyz[(size_t)bm * 3 + 0];
    float qy = new_xyz[(size_t)bm * 3 + 1];
    float qz = new_xyz[(size_t)bm * 3 + 2];

    if (lane == 0) idxS[w][0] = 0;

    unsigned long long below = (1ull << lane) - 1ull;
    int cnt = 0;
    for (int j0 = 0; j0 < NN; j0 += 256) {
        float px[4], py[4], pz[4];
        const float* pp = xyz + ((size_t)(b * NN + j0 + lane)) * 3;
#pragma unroll
        for (int u = 0; u < 4; ++u) {
            px[u] = pp[u * 192 + 0];
            py[u] = pp[u * 192 + 1];
            pz[u] = pp[u * 192 + 2];
        }
#pragma unroll
        for (int u = 0; u < 4; ++u) {
            float d2 = dist2(qx, qy, qz, px[u], py[u], pz[u]);
            bool inshell = (d2 >= R_IN2) && (d2 < R_OUT2);
            unsigned long long mk = __ballot(inshell);
            if (inshell) {
                int r = cnt + __popcll(mk & below);
                if (r < SS) idxS[w][r] = j0 + u * 64 + lane;
            }
            cnt += __popcll(mk);
        }
        if (cnt >= SS) break;
    }
    if (cnt > SS) cnt = SS;
    if (lane == 0) out[bm] = (float)cnt;

    float* gout = out + BB * MM;
    int s = lane & 31, half = lane >> 5;
    int j = (s < cnt) ? idxS[w][s] : idxS[w][0];
    const float* pp = xyz + ((size_t)(b * NN) + j) * 3;
    float px = pp[0], py = pp[1], pz = pp[2];
    float v01 = half ? __fsub_rn(py, qy) : __fsub_rn(px, qx);
    gout[((size_t)(b * 67 + half) * MM + m) * SS + s] = v01;
    if (half == 0) gout[((size_t)(b * 67 + 2) * MM + m) * SS + s] = __fsub_rn(pz, qz);
#pragma unroll
    for (int k = 0; k < 32; ++k) {
        int ch = 2 * k + half;
        float v = features[((size_t)(b * CC + ch)) * NN + j];
        gout[((size_t)(b * 67 + 3 + ch) * MM + m) * SS + s] = v;
    }
}

extern "C" void kernel_launch(void* const* d_in, const int* in_sizes, int n_in,
                              void* d_out, int out_size, void* d_ws, size_t ws_size,
                              hipStream_t stream) {
    const float* xyz = (const float*)d_in[0];
    const float* new_xyz = (const float*)d_in[1];
    const float* features = (const float*)d_in[2];
    float* out = (float*)d_out;

    const size_t featT_bytes = (size_t)BB * NN * CC * 4;   // 8,388,608
    const size_t pidx_bytes = (size_t)BB * MM * SS * 4;    // 524,288
    const size_t pcnt_bytes = (size_t)BB * MM * 4;         // 16,384
    bool fast = ws_size >= featT_bytes + pidx_bytes + pcnt_bytes;

    if (fast) {
        float* feat_t = (float*)d_ws;
        int* pidx = (int*)((char*)d_ws + featT_bytes);
        int* pcnt = (int*)((char*)d_ws + featT_bytes + pidx_bytes);
        transpose_feat<<<2048, 256, 0, stream>>>(features, feat_t);
        k1_scan_group<<<BB * MM / WPB, 256, 0, stream>>>(xyz, new_xyz, feat_t, pcnt, pidx, out);
        k2_finish<<<BB * MM, 512, 0, stream>>>(xyz, new_xyz, feat_t, pcnt, pidx, out);
    } else {
        query_group_fallback<<<BB * MM / 4, 256, 0, stream>>>(xyz, new_xyz, features, out);
    }
}